// Round 4
// baseline (275.733 us; speedup 1.0000x reference)
//
#include <hip/hip_runtime.h>
#include <hip/hip_bf16.h>

#define EPS 1e-5f

// ---------- bf16 helpers (RNE) ----------
__device__ __forceinline__ unsigned short f2bf(float f) {
    unsigned int u = __builtin_bit_cast(unsigned int, f);
    unsigned int r = u + 0x7FFFu + ((u >> 16) & 1u);
    return (unsigned short)(r >> 16);
}
__device__ __forceinline__ float bf2f(unsigned short b) {
    unsigned int u = ((unsigned int)b) << 16;
    return __builtin_bit_cast(float, u);
}

typedef __attribute__((ext_vector_type(8))) short short8;
typedef __attribute__((ext_vector_type(4))) float floatx4;

// async global->LDS, 16B per lane; LDS dest = wave-uniform base + lane*16
__device__ __forceinline__ void gload16(const void* g, void* l) {
    __builtin_amdgcn_global_load_lds(
        (const __attribute__((address_space(1))) unsigned int*)g,
        (__attribute__((address_space(3))) unsigned int*)l,
        16, 0, 0);
}

// =====================================================================
// Pass 0a: W fp32 [256][256] -> bf16 (k-contiguous, ready for MFMA A)
// =====================================================================
__global__ __launch_bounds__(256) void cast_w_kernel(
    const float* __restrict__ w, unsigned short* __restrict__ wb)
{
    int idx = (blockIdx.x * 256 + threadIdx.x) * 4;
    float4 v = *reinterpret_cast<const float4*>(w + idx);
    *reinterpret_cast<ushort4*>(wb + idx) =
        make_ushort4(f2bf(v.x), f2bf(v.y), f2bf(v.z), f2bf(v.w));
}

// =====================================================================
// Pass 0b: xT[b*10240+p][c] bf16  <-  x[b][c][p] fp32   (64x64 LDS tiles)
// =====================================================================
#define TS 72   // LDS tile row stride in shorts (144B, 16B-multiple)

__global__ __launch_bounds__(256) void transpose_x_kernel(
    const float* __restrict__ x, unsigned short* __restrict__ xT)
{
    const int pt = blockIdx.x;   // 0..159 (64 pixels)
    const int ct = blockIdx.y;   // 0..3   (64 channels)
    const int b  = blockIdx.z;
    const int tid = threadIdx.x;

    __shared__ unsigned short T[64 * TS];   // T[p][c]

    const int p0 = pt * 64, c0 = ct * 64;
    const float* xb = x + ((size_t)b * 256 + c0) * 10240 + p0;

    // read: 64 c-rows x 64 p, float4 per load; thread -> (cc=tid/4, 16 p)
    {
        const int cc  = tid >> 2;
        const int pb  = (tid & 3) * 16;
        const float* src = xb + (size_t)cc * 10240 + pb;
#pragma unroll
        for (int it = 0; it < 4; it++) {
            float4 v = *reinterpret_cast<const float4*>(src + it * 4);
            T[(pb + it * 4 + 0) * TS + cc] = f2bf(v.x);
            T[(pb + it * 4 + 1) * TS + cc] = f2bf(v.y);
            T[(pb + it * 4 + 2) * TS + cc] = f2bf(v.z);
            T[(pb + it * 4 + 3) * TS + cc] = f2bf(v.w);
        }
    }
    __syncthreads();

    // write: 64 p-rows x 64 c bf16, 16B per slot (8 slots/row)
    unsigned short* dst = xT + ((size_t)b * 10240 + p0) * 256 + c0;
#pragma unroll
    for (int it = 0; it < 2; it++) {
        int slot = tid + it * 256;
        int pp = slot >> 3, sg = slot & 7;
        *reinterpret_cast<uint4*>(dst + (size_t)pp * 256 + sg * 8) =
            *reinterpret_cast<const uint4*>(&T[pp * TS + sg * 8]);
    }
}

// =====================================================================
// Kernel A (async): y = relu(bn(W @ x)), staging via global_load_lds.
// A = Wb[o][c] bf16, B = xT[p][c] bf16 (both k-contiguous). No pad
// (global_load_lds requires contiguous lane order). 128x128 tile, BK=32.
// =====================================================================
__global__ __launch_bounds__(256) void conv1x1_gemm_async(
    const unsigned short* __restrict__ xT,
    const unsigned short* __restrict__ Wb,
    const float* __restrict__ cb,
    const float* __restrict__ gamma, const float* __restrict__ beta,
    const float* __restrict__ mean,  const float* __restrict__ var,
    unsigned short* __restrict__ y)
{
    const int nt  = blockIdx.x >> 1;
    const int mb  = blockIdx.x & 1;
    const int b   = blockIdx.z;
    const int tid = threadIdx.x;

    __shared__ unsigned short Al[128 * 32];  // [m][k] 64B rows
    __shared__ unsigned short Bl[128 * 32];  // [n][k]
    __shared__ float s1[128], u1[128];

    const int m0 = mb * 128;
    const int p0 = nt * 128;

    if (tid < 128) {
        int o = m0 + tid;
        float s = gamma[o] * rsqrtf(var[o] + EPS);
        s1[tid] = s;
        u1[tid] = cb[o] * s + beta[o] - mean[o] * s;
    }

    const int lane = tid & 63;
    const int wv   = tid >> 6;
    const int lm   = lane & 15;
    const int lq   = lane >> 4;
    const int wm   = (wv & 1) * 64;
    const int wn   = (wv >> 1) * 64;

    // staging: wave wv covers rows [wv*32, wv*32+32); lane -> (row=l/4, k8=l%4)
    const int srow = wv * 32 + (lane >> 2);
    const int kg   = (lane & 3) * 8;
    const unsigned short* gA = Wb + (size_t)(m0 + srow) * 256 + kg;
    const unsigned short* gB = xT + ((size_t)b * 10240 + p0 + srow) * 256 + kg;
    unsigned short* lA0 = &Al[(wv * 32) * 32];
    unsigned short* lA1 = &Al[(wv * 32 + 16) * 32];
    unsigned short* lB0 = &Bl[(wv * 32) * 32];
    unsigned short* lB1 = &Bl[(wv * 32 + 16) * 32];

    floatx4 acc[4][4];
#pragma unroll
    for (int i = 0; i < 4; i++)
#pragma unroll
        for (int j = 0; j < 4; j++) acc[i][j] = (floatx4)0.0f;

#pragma unroll
    for (int k0 = 0; k0 < 256; k0 += 32) {
        __syncthreads();
        gload16(gA + k0, lA0);
        gload16(gA + 16 * 256 + k0, lA1);
        gload16(gB + k0, lB0);
        gload16(gB + 16 * 256 + k0, lB1);
        __syncthreads();   // compiler drains vmcnt before barrier

        short8 af[4], bfr[4];
#pragma unroll
        for (int i = 0; i < 4; i++)
            af[i] = *reinterpret_cast<const short8*>(&Al[(wm + i * 16 + lm) * 32 + lq * 8]);
#pragma unroll
        for (int j = 0; j < 4; j++)
            bfr[j] = *reinterpret_cast<const short8*>(&Bl[(wn + j * 16 + lm) * 32 + lq * 8]);
#pragma unroll
        for (int i = 0; i < 4; i++)
#pragma unroll
            for (int j = 0; j < 4; j++)
                acc[i][j] = __builtin_amdgcn_mfma_f32_16x16x32_bf16(
                    af[i], bfr[j], acc[i][j], 0, 0, 0);
    }

    unsigned short* yb = y + (size_t)b * 256 * 10240;
#pragma unroll
    for (int i = 0; i < 4; i++) {
        int mo_base = wm + i * 16 + lq * 4;
#pragma unroll
        for (int j = 0; j < 4; j++) {
            int p = p0 + wn + j * 16 + lm;
#pragma unroll
            for (int r = 0; r < 4; r++) {
                int mo = mo_base + r;
                float v = acc[i][j][r] * s1[mo] + u1[mo];
                v = fmaxf(v, 0.0f);
                yb[(size_t)(m0 + mo) * 10240 + p] = f2bf(v);
            }
        }
    }
}

// =====================================================================
// Fallback Kernel A (if ws too small for xT): round-2 staged GEMM.
// =====================================================================
#define SK 40
__global__ __launch_bounds__(256) void conv1x1_bn_relu_fb(
    const float* __restrict__ x,
    const float* __restrict__ w,
    const float* __restrict__ cb,
    const float* __restrict__ gamma, const float* __restrict__ beta,
    const float* __restrict__ mean,  const float* __restrict__ var,
    unsigned short* __restrict__ y)
{
    const int nt  = blockIdx.x >> 1;
    const int mb  = blockIdx.x & 1;
    const int b   = blockIdx.z;
    const int tid = threadIdx.x;

    __shared__ unsigned short Al[128 * SK];
    __shared__ unsigned short Bl[128 * SK];
    __shared__ float s1[128], u1[128];

    const int m0 = mb * 128;
    const int p0 = nt * 128;

    if (tid < 128) {
        int o = m0 + tid;
        float s = gamma[o] * rsqrtf(var[o] + EPS);
        s1[tid] = s;
        u1[tid] = cb[o] * s + beta[o] - mean[o] * s;
    }
    const float* xb = x + (size_t)b * 256 * 10240;

    floatx4 acc[4][4];
#pragma unroll
    for (int i = 0; i < 4; i++)
#pragma unroll
        for (int j = 0; j < 4; j++) acc[i][j] = (floatx4)0.0f;

    const int lane = tid & 63;
    const int wv   = tid >> 6;
    const int wm   = (wv & 1) * 64;
    const int wn   = (wv >> 1) * 64;
    const int lm   = lane & 15;
    const int lq   = lane >> 4;
    const int nB = tid & 127;
    const int kB = (tid >> 7) * 4;

    for (int k0 = 0; k0 < 256; k0 += 32) {
        __syncthreads();
        {
            int id = tid;
#pragma unroll
            for (int it = 0; it < 4; it++, id += 256) {
                int m = id >> 3, f4 = id & 7;
                float4 v = *reinterpret_cast<const float4*>(
                    w + (size_t)(m0 + m) * 256 + k0 + f4 * 4);
                *reinterpret_cast<ushort4*>(&Al[m * SK + f4 * 4]) =
                    make_ushort4(f2bf(v.x), f2bf(v.y), f2bf(v.z), f2bf(v.w));
            }
        }
        {
            int kb = kB;
#pragma unroll
            for (int it = 0; it < 4; it++, kb += 8) {
                float v0 = xb[(size_t)(k0 + kb + 0) * 10240 + p0 + nB];
                float v1 = xb[(size_t)(k0 + kb + 1) * 10240 + p0 + nB];
                float v2 = xb[(size_t)(k0 + kb + 2) * 10240 + p0 + nB];
                float v3 = xb[(size_t)(k0 + kb + 3) * 10240 + p0 + nB];
                *reinterpret_cast<ushort4*>(&Bl[nB * SK + kb]) =
                    make_ushort4(f2bf(v0), f2bf(v1), f2bf(v2), f2bf(v3));
            }
        }
        __syncthreads();
        short8 af[4], bfr[4];
#pragma unroll
        for (int i = 0; i < 4; i++)
            af[i] = *reinterpret_cast<const short8*>(&Al[(wm + i * 16 + lm) * SK + lq * 8]);
#pragma unroll
        for (int j = 0; j < 4; j++)
            bfr[j] = *reinterpret_cast<const short8*>(&Bl[(wn + j * 16 + lm) * SK + lq * 8]);
#pragma unroll
        for (int i = 0; i < 4; i++)
#pragma unroll
            for (int j = 0; j < 4; j++)
                acc[i][j] = __builtin_amdgcn_mfma_f32_16x16x32_bf16(
                    af[i], bfr[j], acc[i][j], 0, 0, 0);
    }
    unsigned short* yb = y + (size_t)b * 256 * 10240;
#pragma unroll
    for (int i = 0; i < 4; i++) {
        int mo_base = wm + i * 16 + lq * 4;
#pragma unroll
        for (int j = 0; j < 4; j++) {
            int p = p0 + wn + j * 16 + lm;
#pragma unroll
            for (int r = 0; r < 4; r++) {
                int mo = mo_base + r;
                float v = acc[i][j][r] * s1[mo] + u1[mo];
                yb[(size_t)(m0 + mo) * 10240 + p] = f2bf(fmaxf(v, 0.0f));
            }
        }
    }
}

// =====================================================================
// Kernel B: round-2 structure (measured best: 73 us) + div-free step1.
// =====================================================================
#define YS 52
#define QS 52

__global__ __launch_bounds__(256) void refine_accum(
    const float* __restrict__ x,
    const unsigned short* __restrict__ y,
    const float* __restrict__ rw,
    const float* __restrict__ rb,
    const float* __restrict__ rg, const float* __restrict__ rbe,
    const float* __restrict__ rm, const float* __restrict__ rv,
    float* __restrict__ out)
{
    const int bi    = blockIdx.x;
    const int strip = bi & 3;
    const int c     = (bi >> 2) & 255;
    const int b     = bi >> 10;
    const int c0    = strip * 40;
    const int tid   = threadIdx.x;

    __shared__ float yt[64 * YS];   // col j <-> w = c0-5+j (mod 160)
    __shared__ float qt[64 * QS];   // col qc <-> w = c0-4+qc

    const size_t img = ((size_t)b * 256 + c) * 10240;
    const unsigned short* yp = y + img;

    float w9[9];
#pragma unroll
    for (int t = 0; t < 9; t++) w9[t] = rw[c * 9 + t];
    const float s2 = rg[c] * rsqrtf(rv[c] + EPS);
    const float u2 = rb[c] * s2 + rbe[c] - rm[c] * s2;

    // ---- step1 (div-free): thread -> (row = tid>>2, 13 contiguous cols)
    {
        const int r  = tid >> 2;
        const int j0 = (tid & 3) * 13;
        const unsigned short* yrow = yp + r * 160;
        float* drow = &yt[r * YS + j0];
        const bool mayWrap = (c0 == 0) || (c0 == 120);
        if (!mayWrap) {
            const unsigned short* s = yrow + (c0 - 5 + j0);
#pragma unroll
            for (int i = 0; i < 13; i++) drow[i] = bf2f(s[i]);
        } else {
#pragma unroll
            for (int i = 0; i < 13; i++) {
                int gw = c0 - 5 + j0 + i;
                if (gw < 0) gw += 160; else if (gw >= 160) gw -= 160;
                drow[i] = bf2f(yrow[gw]);
            }
        }
    }
    __syncthreads();

    // ---- step2: q = relu(bn(circular conv3x3)), 1 row x 4 cols per task
    for (int t = tid; t < 64 * 12; t += 256) {
        int r = t / 12, g = t - r * 12;
        int q0 = 4 * g;
        int rm1 = (r + 63) & 63, rp1 = (r + 1) & 63;
        float A[8], B[8], C[8];
        *reinterpret_cast<float4*>(&A[0]) = *reinterpret_cast<const float4*>(&yt[rm1 * YS + q0]);
        *reinterpret_cast<float4*>(&A[4]) = *reinterpret_cast<const float4*>(&yt[rm1 * YS + q0 + 4]);
        *reinterpret_cast<float4*>(&B[0]) = *reinterpret_cast<const float4*>(&yt[r   * YS + q0]);
        *reinterpret_cast<float4*>(&B[4]) = *reinterpret_cast<const float4*>(&yt[r   * YS + q0 + 4]);
        *reinterpret_cast<float4*>(&C[0]) = *reinterpret_cast<const float4*>(&yt[rp1 * YS + q0]);
        *reinterpret_cast<float4*>(&C[4]) = *reinterpret_cast<const float4*>(&yt[rp1 * YS + q0 + 4]);
        float4 qv;
        float* qvp = reinterpret_cast<float*>(&qv);
#pragma unroll
        for (int i = 0; i < 4; i++) {
            float z = w9[0] * A[i] + w9[1] * A[i + 1] + w9[2] * A[i + 2]
                    + w9[3] * B[i] + w9[4] * B[i + 1] + w9[5] * B[i + 2]
                    + w9[6] * C[i] + w9[7] * C[i + 1] + w9[8] * C[i + 2];
            qvp[i] = fmaxf(z * s2 + u2, 0.0f);
        }
        *reinterpret_cast<float4*>(&qt[r * QS + q0]) = qv;
    }
    __syncthreads();

    const float w1 = 0.80073740f, w2 = 0.41111229f, w3 = 0.13533528f;
    const float SCALE = 0.5f / (4.0f * (w1 + w2 + w3));

    // ---- step3: interior formula, 4 outputs per task
    for (int t = tid; t < 64 * 10; t += 256) {
        int r = t / 10, g = t - r * 10;
        int qb = 4 * g + 4;
        float vm1[4], vm2[4], vm3[4], vp1[4], vp2[4], vp3[4], H[12];
        *reinterpret_cast<float4*>(&vm1[0]) = *reinterpret_cast<const float4*>(&qt[((r + 63) & 63) * QS + qb]);
        *reinterpret_cast<float4*>(&vm2[0]) = *reinterpret_cast<const float4*>(&qt[((r + 62) & 63) * QS + qb]);
        *reinterpret_cast<float4*>(&vm3[0]) = *reinterpret_cast<const float4*>(&qt[((r + 61) & 63) * QS + qb]);
        *reinterpret_cast<float4*>(&vp1[0]) = *reinterpret_cast<const float4*>(&qt[((r + 1) & 63) * QS + qb]);
        *reinterpret_cast<float4*>(&vp2[0]) = *reinterpret_cast<const float4*>(&qt[((r + 2) & 63) * QS + qb]);
        *reinterpret_cast<float4*>(&vp3[0]) = *reinterpret_cast<const float4*>(&qt[((r + 3) & 63) * QS + qb]);
        *reinterpret_cast<float4*>(&H[0])  = *reinterpret_cast<const float4*>(&qt[r * QS + qb - 4]);
        *reinterpret_cast<float4*>(&H[4])  = *reinterpret_cast<const float4*>(&qt[r * QS + qb]);
        *reinterpret_cast<float4*>(&H[8])  = *reinterpret_cast<const float4*>(&qt[r * QS + qb + 4]);

        int h = r, w0 = c0 + 4 * g;
        size_t gidx = img + (size_t)h * 160 + w0;
        float4 xv = *reinterpret_cast<const float4*>(&x[gidx]);
        const float* xvp = reinterpret_cast<const float*>(&xv);
        float ov[4];
#pragma unroll
        for (int i = 0; i < 4; i++) {
            float vs = w1 * (vm1[i] + vp1[i]) + w2 * (vm2[i] + vp2[i]) + w3 * (vm3[i] + vp3[i]);
            float hs = w1 * (H[i + 3] + H[i + 5]) + w2 * (H[i + 2] + H[i + 6]) + w3 * (H[i + 1] + H[i + 7]);
            ov[i] = xvp[i] + SCALE * (vs + hs);
        }
        bool rowok = (h != 0) && (h != 63);
        if (rowok) {
            if (c0 == 0 && g == 0) {
                out[gidx + 1] = ov[1]; out[gidx + 2] = ov[2]; out[gidx + 3] = ov[3];
            } else if (c0 == 120 && g == 9) {
                out[gidx] = ov[0]; out[gidx + 1] = ov[1]; out[gidx + 2] = ov[2];
            } else {
                *reinterpret_cast<float4*>(&out[gidx]) =
                    make_float4(ov[0], ov[1], ov[2], ov[3]);
            }
        }
    }

    // ---- step4: border fixup
    const int SH[12] = {1, 2, 3, -1, -2, -3, 0, 0, 0, 0, 0, 0};
    const int SW[12] = {0, 0, 0, 0, 0, 0, -1, -2, -3, 1, 2, 3};
    const float WT[12] = {w1, w2, w3, w1, w2, w3, w1, w2, w3, w1, w2, w3};
    const bool edge = (c0 == 0) || (c0 == 120);
    const int nb = 80 + (edge ? 62 : 0);
    if (tid < nb) {
        int h, w;
        if (tid < 40)      { h = 0;  w = c0 + tid; }
        else if (tid < 80) { h = 63; w = c0 + tid - 40; }
        else               { h = tid - 79; w = (c0 == 0) ? 0 : 159; }
        float mw[9];
#pragma unroll
        for (int dh = 0; dh < 3; dh++)
#pragma unroll
            for (int dw = 0; dw < 3; dw++) {
                int ih = h + dh - 1, iw = w + dw - 1;
                mw[dh * 3 + dw] =
                    (ih >= 0 && ih < 64 && iw >= 0 && iw < 160) ? w9[dh * 3 + dw] : 0.0f;
            }
        float accv = 0.0f;
#pragma unroll
        for (int s = 0; s < 12; s++) {
            float conv = 0.0f;
#pragma unroll
            for (int dh = 0; dh < 3; dh++)
#pragma unroll
                for (int dw = 0; dw < 3; dw++) {
                    int row = (h + dh - 1 - SH[s]) & 63;
                    int jj  = (w - c0) + dw + 4 - SW[s];
                    conv += mw[dh * 3 + dw] * yt[row * YS + jj];
                }
            accv += WT[s] * fmaxf(conv * s2 + u2, 0.0f);
        }
        size_t gidx = img + (size_t)h * 160 + w;
        out[gidx] = x[gidx] + SCALE * accv;
    }
}

extern "C" void kernel_launch(void* const* d_in, const int* in_sizes, int n_in,
                              void* d_out, int out_size, void* d_ws, size_t ws_size,
                              hipStream_t stream) {
    const float* x      = (const float*)d_in[0];
    const float* conv_w = (const float*)d_in[1];
    const float* conv_b = (const float*)d_in[2];
    const float* bn_g   = (const float*)d_in[3];
    const float* bn_b   = (const float*)d_in[4];
    const float* bn_m   = (const float*)d_in[5];
    const float* bn_v   = (const float*)d_in[6];
    const float* ref_w  = (const float*)d_in[7];
    const float* ref_b  = (const float*)d_in[8];
    const float* rbn_g  = (const float*)d_in[9];
    const float* rbn_b  = (const float*)d_in[10];
    const float* rbn_m  = (const float*)d_in[11];
    const float* rbn_v  = (const float*)d_in[12];
    float* out          = (float*)d_out;

    const size_t Y_BYTES  = (size_t)8 * 256 * 10240 * 2;   // 41,943,040
    const size_t XT_BYTES = Y_BYTES;
    const size_t W_BYTES  = 256 * 256 * 2;

    unsigned short* y_ws = (unsigned short*)d_ws;

    if (ws_size >= Y_BYTES + XT_BYTES + W_BYTES) {
        unsigned short* xT = (unsigned short*)((char*)d_ws + Y_BYTES);
        unsigned short* Wb = (unsigned short*)((char*)d_ws + Y_BYTES + XT_BYTES);
        cast_w_kernel<<<dim3(64), 256, 0, stream>>>(conv_w, Wb);
        transpose_x_kernel<<<dim3(160, 4, 8), 256, 0, stream>>>(x, xT);
        conv1x1_gemm_async<<<dim3(160, 1, 8), 256, 0, stream>>>(
            xT, Wb, conv_b, bn_g, bn_b, bn_m, bn_v, y_ws);
    } else {
        conv1x1_bn_relu_fb<<<dim3(160, 1, 8), 256, 0, stream>>>(
            x, conv_w, conv_b, bn_g, bn_b, bn_m, bn_v, y_ws);
    }

    refine_accum<<<dim3(8 * 256 * 4), 256, 0, stream>>>(
        x, y_ws, ref_w, ref_b, rbn_g, rbn_b, rbn_m, rbn_v, out);
}